// Round 8
// baseline (206.712 us; speedup 1.0000x reference)
//
#include <hip/hip_runtime.h>

#define NB 16
#define T 16000
#define NF 64
#define TILE 252              // output timesteps per block
#define TT 256                // threads per block
#define HALO 32
#define ROWS (TILE + HALO)    // 284
#define RSU 18                // per-pass row stride in dwords: L dw 0..7, R dw 8..15, pad 2
#define N_ITD 16
#define N_ILD 8

typedef _Float16 half2_t __attribute__((ext_vector_type(2)));

__device__ __forceinline__ unsigned int pk2h(float a, float b) {
    half2_t h;
    h.x = (_Float16)a;
    h.y = (_Float16)b;
    return __builtin_bit_cast(unsigned int, h);
}
__device__ __forceinline__ float dot2(unsigned int a, unsigned int b, float c) {
    return __builtin_amdgcn_fdot2(__builtin_bit_cast(half2_t, a),
                                  __builtin_bit_cast(half2_t, b), c, false);
}

// Double-buffered 4-pass (16ch each) pipeline, r5 structure de-spilled:
//  - named scalar float4 staging regs (NO arrays/lambdas -> nothing hits scratch)
//  - __launch_bounds__(256,3): 170-VGPR cap, ~110 used
//  - LDS = 2 * 284*18*4 = 40896 B -> 3 blocks/CU = 12 waves/CU
// Loads for pass p issue before compute of pass p-1; pack+write after -> T14.
__global__ __launch_bounds__(TT, 3) void biaural_kernel(const float* __restrict__ L,
                                                        const float* __restrict__ R,
                                                        float* __restrict__ out) {
    __shared__ unsigned int sh[2][ROWS * RSU];

    const int b = blockIdx.y;
    const int t0 = blockIdx.x * TILE;
    const int tid = threadIdx.x;

    const float* __restrict__ Lb = L + (size_t)b * T * NF;
    const float* __restrict__ Rb = R + (size_t)b * T * NF;

    // staging decode: unit n = tid + 256*it -> row = (tid>>2) + 64*it, q = tid&3
    // q 0,1 -> left ear chunk 0/1 ; q 2,3 -> right ear chunk 0/1
    const int q = tid & 3;
    const float* __restrict__ eb = (q < 2) ? Lb : Rb;
    const int cf0 = (q & 1) * 8;
    const int r0 = tid >> 2;

    const int row0 = r0;        const int gt0 = t0 - HALO + row0;
    const int row1 = r0 + 64;   const int gt1 = gt0 + 64;
    const int row2 = r0 + 128;  const int gt2 = gt0 + 128;
    const int row3 = r0 + 192;  const int gt3 = gt0 + 192;
    const int row4 = r0 + 256;  const int gt4 = gt0 + 256;   // written only if tid<112

    float acc[N_ITD];
#pragma unroll
    for (int i = 0; i < N_ITD; ++i) acc[i] = 0.f;
    float sumL = 0.f, sumR = 0.f;

    const int OFF[8] = {2, 6, 11, 15, 19, 23, 28, 32};
    const unsigned int ONE2 = 0x3C003C00u;   // (1.0h, 1.0h)
    const int ct = (tid < TILE) ? tid : (TILE - 1);
    const int cb = (HALO + ct) * RSU;

    float4 ua0, ub0, ua1, ub1, ua2, ub2, ua3, ub3, ua4, ub4;

#define CLT(g) ((g) < 0 ? 0 : ((g) >= T ? (T - 1) : (g)))

#define STAGE_ISSUE(p) do {                                                   \
    const float* s0 = eb + (size_t)CLT(gt0) * NF + (p) * 16 + cf0;            \
    const float* s1 = eb + (size_t)CLT(gt1) * NF + (p) * 16 + cf0;            \
    const float* s2 = eb + (size_t)CLT(gt2) * NF + (p) * 16 + cf0;            \
    const float* s3 = eb + (size_t)CLT(gt3) * NF + (p) * 16 + cf0;            \
    const float* s4 = eb + (size_t)CLT(gt4) * NF + (p) * 16 + cf0;            \
    ua0 = *(const float4*)s0; ub0 = *(const float4*)(s0 + 4);                 \
    ua1 = *(const float4*)s1; ub1 = *(const float4*)(s1 + 4);                 \
    ua2 = *(const float4*)s2; ub2 = *(const float4*)(s2 + 4);                 \
    ua3 = *(const float4*)s3; ub3 = *(const float4*)(s3 + 4);                 \
    ua4 = *(const float4*)s4; ub4 = *(const float4*)(s4 + 4);                 \
} while (0)

#define WR1(bi, row, gt, ua, ub) do {                                         \
    const unsigned int vm = ((gt) >= 0 && (gt) < T) ? 0xFFFFFFFFu : 0u;       \
    uint4 pk;                                                                 \
    pk.x = pk2h((ua).x, (ua).y) & vm; pk.y = pk2h((ua).z, (ua).w) & vm;       \
    pk.z = pk2h((ub).x, (ub).y) & vm; pk.w = pk2h((ub).z, (ub).w) & vm;       \
    *(uint4*)&sh[bi][(row) * RSU + q * 4] = pk;                               \
} while (0)

#define STAGE_WRITE(bi) do {                                                  \
    WR1(bi, row0, gt0, ua0, ub0);                                             \
    WR1(bi, row1, gt1, ua1, ub1);                                             \
    WR1(bi, row2, gt2, ua2, ub2);                                             \
    WR1(bi, row3, gt3, ua3, ub3);                                             \
    if (tid < 112) { WR1(bi, row4, gt4, ua4, ub4); }                          \
} while (0)

#define COMPUTE(bi) do {                                                      \
    const unsigned int* s = &sh[bi][0];                                       \
    const uint4 lcA = *(const uint4*)&s[cb + 0];                              \
    const uint4 lcB = *(const uint4*)&s[cb + 4];                              \
    const uint4 rcA = *(const uint4*)&s[cb + 8];                              \
    const uint4 rcB = *(const uint4*)&s[cb + 12];                             \
    sumL = dot2(lcA.x, ONE2, sumL); sumL = dot2(lcA.y, ONE2, sumL);           \
    sumL = dot2(lcA.z, ONE2, sumL); sumL = dot2(lcA.w, ONE2, sumL);           \
    sumL = dot2(lcB.x, ONE2, sumL); sumL = dot2(lcB.y, ONE2, sumL);           \
    sumL = dot2(lcB.z, ONE2, sumL); sumL = dot2(lcB.w, ONE2, sumL);           \
    sumR = dot2(rcA.x, ONE2, sumR); sumR = dot2(rcA.y, ONE2, sumR);           \
    sumR = dot2(rcA.z, ONE2, sumR); sumR = dot2(rcA.w, ONE2, sumR);           \
    sumR = dot2(rcB.x, ONE2, sumR); sumR = dot2(rcB.y, ONE2, sumR);           \
    sumR = dot2(rcB.z, ONE2, sumR); sumR = dot2(rcB.w, ONE2, sumR);           \
    _Pragma("unroll")                                                         \
    for (int k = 0; k < 8; ++k) {                                             \
        const int rb = cb - OFF[k] * RSU;                                     \
        const uint4 laA = *(const uint4*)&s[rb + 0];                          \
        const uint4 laB = *(const uint4*)&s[rb + 4];                          \
        acc[8 + k] = dot2(laA.x, rcA.x, acc[8 + k]);                          \
        acc[8 + k] = dot2(laA.y, rcA.y, acc[8 + k]);                          \
        acc[8 + k] = dot2(laA.z, rcA.z, acc[8 + k]);                          \
        acc[8 + k] = dot2(laA.w, rcA.w, acc[8 + k]);                          \
        acc[8 + k] = dot2(laB.x, rcB.x, acc[8 + k]);                          \
        acc[8 + k] = dot2(laB.y, rcB.y, acc[8 + k]);                          \
        acc[8 + k] = dot2(laB.z, rcB.z, acc[8 + k]);                          \
        acc[8 + k] = dot2(laB.w, rcB.w, acc[8 + k]);                          \
        const uint4 raA = *(const uint4*)&s[rb + 8];                          \
        const uint4 raB = *(const uint4*)&s[rb + 12];                         \
        acc[7 - k] = dot2(lcA.x, raA.x, acc[7 - k]);                          \
        acc[7 - k] = dot2(lcA.y, raA.y, acc[7 - k]);                          \
        acc[7 - k] = dot2(lcA.z, raA.z, acc[7 - k]);                          \
        acc[7 - k] = dot2(lcA.w, raA.w, acc[7 - k]);                          \
        acc[7 - k] = dot2(lcB.x, raB.x, acc[7 - k]);                          \
        acc[7 - k] = dot2(lcB.y, raB.y, acc[7 - k]);                          \
        acc[7 - k] = dot2(lcB.z, raB.z, acc[7 - k]);                          \
        acc[7 - k] = dot2(lcB.w, raB.w, acc[7 - k]);                          \
    }                                                                         \
} while (0)

    // pipeline: one barrier per pass; loads of pass p in flight under compute p-1
    STAGE_ISSUE(0);
    STAGE_WRITE(0);
    __syncthreads();

    STAGE_ISSUE(1);
    COMPUTE(0);
    STAGE_WRITE(1);
    __syncthreads();

    STAGE_ISSUE(2);
    COMPUTE(1);
    STAGE_WRITE(0);
    __syncthreads();

    STAGE_ISSUE(3);
    COMPUTE(0);
    STAGE_WRITE(1);
    __syncthreads();

    COMPUTE(1);

    const int t = t0 + tid;
    if (tid < TILE && t < T) {
        // ---- ITD: [B,T,16]
        float* oitd = out + ((size_t)b * T + t) * N_ITD;
#pragma unroll
        for (int qq = 0; qq < 4; ++qq) {
            *(float4*)(oitd + qq * 4) =
                make_float4(acc[qq * 4 + 0], acc[qq * 4 + 1], acc[qq * 4 + 2], acc[qq * 4 + 3]);
        }

        // ---- ILD: [B,T,8] after the ITD block
        const float ild = (sumL - sumR) / (sumL + sumR + 1e-6f);
        const float PREFS[8] = {-1.f, -0.71428573f, -0.42857143f, -0.14285714f,
                                0.14285715f, 0.42857143f, 0.71428573f, 1.f};
        float ov[8];
#pragma unroll
        for (int j = 0; j < 8; ++j) {
            const float z = (ild - PREFS[j]) * (1.0f / 0.3f);
            ov[j] = __expf(-0.5f * z * z);
        }
        float* oild = out + (size_t)NB * T * N_ITD + ((size_t)b * T + t) * N_ILD;
        *(float4*)(oild + 0) = make_float4(ov[0], ov[1], ov[2], ov[3]);
        *(float4*)(oild + 4) = make_float4(ov[4], ov[5], ov[6], ov[7]);
    }
}

extern "C" void kernel_launch(void* const* d_in, const int* in_sizes, int n_in,
                              void* d_out, int out_size, void* d_ws, size_t ws_size,
                              hipStream_t stream) {
    const float* L = (const float*)d_in[0];
    const float* R = (const float*)d_in[1];
    float* out = (float*)d_out;
    dim3 grid((T + TILE - 1) / TILE, NB);   // 64 x 16
    biaural_kernel<<<grid, dim3(TT), 0, stream>>>(L, R, out);
}

// Round 10
// 39.935 us; speedup vs baseline: 5.1763x; 5.1763x over previous
//
#include <hip/hip_runtime.h>

#define NB 16
#define T 16000
#define NF 64
#define TILE 125              // output timesteps per block (128 x-blocks exactly)
#define TT 128                // threads per block (2 waves)
#define HALO 32
#define ROWS (TILE + HALO)    // 157
#define RSU 36                // row stride in dwords: L dw 0..15, R dw 16..31, pad 4
#define N_ITD 16
#define N_ILD 8

typedef _Float16 half2_t __attribute__((ext_vector_type(2)));
typedef float f4 __attribute__((ext_vector_type(4)));   // nontemporal-store-compatible

__device__ __forceinline__ unsigned int pk2h(float a, float b) {
    half2_t h;
    h.x = (_Float16)a;
    h.y = (_Float16)b;
    return __builtin_bit_cast(unsigned int, h);
}
__device__ __forceinline__ float dot2(unsigned int a, unsigned int b, float c) {
    return __builtin_amdgcn_fdot2(__builtin_bit_cast(half2_t, a),
                                  __builtin_bit_cast(half2_t, b), c, false);
}
__device__ __forceinline__ void nt_store4(float* p, float x, float y, float z, float w) {
    f4 v = {x, y, z, w};
    __builtin_nontemporal_store(v, (f4*)p);
}

// r3 structure, two changes:
//  (1) nontemporal output stores: 24 MB/dispatch of outputs bypass L3 so the
//      131 MB of inputs stay L3-resident across graph replays (FETCH 72 -> low)
//  (2) LDS = 157*36*4 = 22608 B -> 7 blocks/CU (2-wave barrier domains,
//      decorrelated stage/compute phases)
// Staging loop keeps r3's fractional-trip form (628/128 = 4.9 iters): exact-trip
// versions fully unroll and spill (rounds 4/5/6/8, WRITE_SIZE 216-390 MB).
__global__ __launch_bounds__(TT, 3) void biaural_kernel(const float* __restrict__ L,
                                                        const float* __restrict__ R,
                                                        float* __restrict__ out) {
    __shared__ unsigned int sh[ROWS * RSU];

    const int b = blockIdx.y;
    const int t0 = blockIdx.x * TILE;
    const int tid = threadIdx.x;

    const float* __restrict__ Lb = L + (size_t)b * T * NF;
    const float* __restrict__ Rb = R + (size_t)b * T * NF;

    float acc[N_ITD];
#pragma unroll
    for (int i = 0; i < N_ITD; ++i) acc[i] = 0.f;
    float sumL = 0.f, sumR = 0.f;

    const int OFF[8] = {2, 6, 11, 15, 19, 23, 28, 32};
    const unsigned int ONE2 = 0x3C003C00u;   // (1.0h, 1.0h)
    const int ct = (tid < TILE) ? tid : (TILE - 1);
    const int crowbase = (HALO + ct) * RSU;

#pragma unroll
    for (int pass = 0; pass < 2; ++pass) {
        const int pf = pass * 32;            // float offset within the 64-ch row
        if (pass) __syncthreads();           // protect LDS reuse

        // ---- stage [t0-32, t0+TILE-1] x 32ch of both ears as f16 (b128 writes)
        // 157*4/128 = 4.9 iterations; gt < T always (max 15999).
        for (int n = tid; n < ROWS * 4; n += TT) {
            const int row = n >> 2;
            const int c = n & 3;             // 8-float chunk within the 32-ch slab
            const int gt = t0 - HALO + row;
            uint4 pl = make_uint4(0u, 0u, 0u, 0u);
            uint4 pr = make_uint4(0u, 0u, 0u, 0u);
            if (gt >= 0) {
                const float* lp = Lb + (size_t)gt * NF + pf + c * 8;
                const float* rp = Rb + (size_t)gt * NF + pf + c * 8;
                float4 a0 = *(const float4*)lp;
                float4 a1 = *(const float4*)(lp + 4);
                float4 b0 = *(const float4*)rp;
                float4 b1 = *(const float4*)(rp + 4);
                pl = make_uint4(pk2h(a0.x, a0.y), pk2h(a0.z, a0.w),
                                pk2h(a1.x, a1.y), pk2h(a1.z, a1.w));
                pr = make_uint4(pk2h(b0.x, b0.y), pk2h(b0.z, b0.w),
                                pk2h(b1.x, b1.y), pk2h(b1.z, b1.w));
            }
            const int idx = row * RSU + c * 4;
            *(uint4*)&sh[idx] = pl;
            *(uint4*)&sh[idx + 16] = pr;
        }
        __syncthreads();

        // ---- compute: 4 chunks of 8 channels
#pragma unroll
        for (int c = 0; c < 4; ++c) {
            const uint4 lc = *(const uint4*)&sh[crowbase + c * 4];
            const uint4 rc = *(const uint4*)&sh[crowbase + 16 + c * 4];
            sumL = dot2(lc.x, ONE2, sumL); sumL = dot2(lc.y, ONE2, sumL);
            sumL = dot2(lc.z, ONE2, sumL); sumL = dot2(lc.w, ONE2, sumL);
            sumR = dot2(rc.x, ONE2, sumR); sumR = dot2(rc.y, ONE2, sumR);
            sumR = dot2(rc.z, ONE2, sumR); sumR = dot2(rc.w, ONE2, sumR);
#pragma unroll
            for (int k = 0; k < 8; ++k) {
                const int rb = crowbase - OFF[k] * RSU;
                const uint4 la = *(const uint4*)&sh[rb + c * 4];
                acc[8 + k] = dot2(la.x, rc.x, acc[8 + k]);
                acc[8 + k] = dot2(la.y, rc.y, acc[8 + k]);
                acc[8 + k] = dot2(la.z, rc.z, acc[8 + k]);
                acc[8 + k] = dot2(la.w, rc.w, acc[8 + k]);
                const uint4 ra = *(const uint4*)&sh[rb + 16 + c * 4];
                acc[7 - k] = dot2(lc.x, ra.x, acc[7 - k]);
                acc[7 - k] = dot2(lc.y, ra.y, acc[7 - k]);
                acc[7 - k] = dot2(lc.z, ra.z, acc[7 - k]);
                acc[7 - k] = dot2(lc.w, ra.w, acc[7 - k]);
            }
        }
    }

    const int t = t0 + tid;
    if (tid < TILE) {        // t < T guaranteed (127*125+124 = 15999)
        // ---- ITD: [B,T,16] — nontemporal: don't let outputs evict inputs from L3
        float* oitd = out + ((size_t)b * T + t) * N_ITD;
#pragma unroll
        for (int q = 0; q < 4; ++q) {
            nt_store4(oitd + q * 4, acc[q * 4 + 0], acc[q * 4 + 1],
                      acc[q * 4 + 2], acc[q * 4 + 3]);
        }

        // ---- ILD: [B,T,8] after the ITD block
        const float ild = (sumL - sumR) / (sumL + sumR + 1e-6f);
        const float PREFS[8] = {-1.f, -0.71428573f, -0.42857143f, -0.14285714f,
                                0.14285715f, 0.42857143f, 0.71428573f, 1.f};
        float ov[8];
#pragma unroll
        for (int j = 0; j < 8; ++j) {
            const float z = (ild - PREFS[j]) * (1.0f / 0.3f);
            ov[j] = __expf(-0.5f * z * z);
        }
        float* oild = out + (size_t)NB * T * N_ITD + ((size_t)b * T + t) * N_ILD;
        nt_store4(oild + 0, ov[0], ov[1], ov[2], ov[3]);
        nt_store4(oild + 4, ov[4], ov[5], ov[6], ov[7]);
    }
}

extern "C" void kernel_launch(void* const* d_in, const int* in_sizes, int n_in,
                              void* d_out, int out_size, void* d_ws, size_t ws_size,
                              hipStream_t stream) {
    const float* L = (const float*)d_in[0];
    const float* R = (const float*)d_in[1];
    float* out = (float*)d_out;
    dim3 grid(T / TILE, NB);   // 128 x 16 = 2048 blocks, 7 resident/CU
    biaural_kernel<<<grid, dim3(TT), 0, stream>>>(L, R, out);
}

// Round 11
// 35.500 us; speedup vs baseline: 5.8228x; 1.1249x over previous
//
#include <hip/hip_runtime.h>

#define NB 16
#define T 16000
#define NF 64
#define TILE 252              // output timesteps per block
#define TT 256                // threads per block
#define HALO 32
#define ROWS (TILE + HALO)    // 284
#define RSU 36                // row stride in dwords: L dw 0..15, R dw 16..31, pad 4
#define N_ITD 16
#define N_ILD 8

typedef _Float16 half2_t __attribute__((ext_vector_type(2)));

__device__ __forceinline__ unsigned int pk2h(float a, float b) {
    half2_t h;
    h.x = (_Float16)a;
    h.y = (_Float16)b;
    return __builtin_bit_cast(unsigned int, h);
}
__device__ __forceinline__ float dot2(unsigned int a, unsigned int b, float c) {
    return __builtin_amdgcn_fdot2(__builtin_bit_cast(half2_t, a),
                                  __builtin_bit_cast(half2_t, b), c, false);
}

// r3 structure (35.4 us best) with ONE change: staging iterations widened from
// 4 to 8 independent dwordx4 loads each -> 568/256 = 2.2 rolled iterations,
// ~2 serial memory round-trips per pass instead of ~5. #pragma unroll 1
// prevents the exact-trip full-unroll spill seen in rounds 4/5/6/8.
// LDS = 284*36*4 = 40896 B -> 4 blocks/CU.
__global__ __launch_bounds__(TT, 4) void biaural_kernel(const float* __restrict__ L,
                                                        const float* __restrict__ R,
                                                        float* __restrict__ out) {
    __shared__ unsigned int sh[ROWS * RSU];

    const int b = blockIdx.y;
    const int t0 = blockIdx.x * TILE;
    const int tid = threadIdx.x;

    const float* __restrict__ Lb = L + (size_t)b * T * NF;
    const float* __restrict__ Rb = R + (size_t)b * T * NF;

    float acc[N_ITD];
#pragma unroll
    for (int i = 0; i < N_ITD; ++i) acc[i] = 0.f;
    float sumL = 0.f, sumR = 0.f;

    const int OFF[8] = {2, 6, 11, 15, 19, 23, 28, 32};
    const unsigned int ONE2 = 0x3C003C00u;   // (1.0h, 1.0h)
    const int ct = (tid < TILE) ? tid : (TILE - 1);
    const int crowbase = (HALO + ct) * RSU;

#pragma unroll
    for (int pass = 0; pass < 2; ++pass) {
        const int pf = pass * 32;            // float offset within the 64-ch row
        if (pass) __syncthreads();           // protect LDS reuse

        // ---- stage [t0-32, t0+TILE-1] x 32ch of both ears as f16.
        // unit n = (row = n>>1, half = n&1): 16 floats L + 16 floats R = 8
        // independent dwordx4 loads per iteration (deep MLP within the trip).
#pragma unroll 1
        for (int n = tid; n < ROWS * 2; n += TT) {
            const int row = n >> 1;
            const int hf = (n & 1) * 16;     // float offset of the 16-ch half
            const int gt = t0 - HALO + row;
            uint4 la = make_uint4(0u, 0u, 0u, 0u);
            uint4 lb = la, ra = la, rb = la;
            if (gt >= 0) {                   // gt < T always for this grid
                const float* lp = Lb + (size_t)gt * NF + pf + hf;
                const float* rp = Rb + (size_t)gt * NF + pf + hf;
                const float4 a0 = *(const float4*)(lp + 0);
                const float4 a1 = *(const float4*)(lp + 4);
                const float4 a2 = *(const float4*)(lp + 8);
                const float4 a3 = *(const float4*)(lp + 12);
                const float4 b0 = *(const float4*)(rp + 0);
                const float4 b1 = *(const float4*)(rp + 4);
                const float4 b2 = *(const float4*)(rp + 8);
                const float4 b3 = *(const float4*)(rp + 12);
                la = make_uint4(pk2h(a0.x, a0.y), pk2h(a0.z, a0.w),
                                pk2h(a1.x, a1.y), pk2h(a1.z, a1.w));
                lb = make_uint4(pk2h(a2.x, a2.y), pk2h(a2.z, a2.w),
                                pk2h(a3.x, a3.y), pk2h(a3.z, a3.w));
                ra = make_uint4(pk2h(b0.x, b0.y), pk2h(b0.z, b0.w),
                                pk2h(b1.x, b1.y), pk2h(b1.z, b1.w));
                rb = make_uint4(pk2h(b2.x, b2.y), pk2h(b2.z, b2.w),
                                pk2h(b3.x, b3.y), pk2h(b3.z, b3.w));
            }
            const int base = row * RSU + (n & 1) * 8;
            *(uint4*)&sh[base + 0] = la;
            *(uint4*)&sh[base + 4] = lb;
            *(uint4*)&sh[base + 16] = ra;
            *(uint4*)&sh[base + 20] = rb;
        }
        __syncthreads();

        // ---- compute: 4 chunks of 8 channels
#pragma unroll
        for (int c = 0; c < 4; ++c) {
            const uint4 lc = *(const uint4*)&sh[crowbase + c * 4];
            const uint4 rc = *(const uint4*)&sh[crowbase + 16 + c * 4];
            sumL = dot2(lc.x, ONE2, sumL); sumL = dot2(lc.y, ONE2, sumL);
            sumL = dot2(lc.z, ONE2, sumL); sumL = dot2(lc.w, ONE2, sumL);
            sumR = dot2(rc.x, ONE2, sumR); sumR = dot2(rc.y, ONE2, sumR);
            sumR = dot2(rc.z, ONE2, sumR); sumR = dot2(rc.w, ONE2, sumR);
#pragma unroll
            for (int k = 0; k < 8; ++k) {
                const int rb2 = crowbase - OFF[k] * RSU;
                const uint4 la = *(const uint4*)&sh[rb2 + c * 4];
                acc[8 + k] = dot2(la.x, rc.x, acc[8 + k]);
                acc[8 + k] = dot2(la.y, rc.y, acc[8 + k]);
                acc[8 + k] = dot2(la.z, rc.z, acc[8 + k]);
                acc[8 + k] = dot2(la.w, rc.w, acc[8 + k]);
                const uint4 ra = *(const uint4*)&sh[rb2 + 16 + c * 4];
                acc[7 - k] = dot2(lc.x, ra.x, acc[7 - k]);
                acc[7 - k] = dot2(lc.y, ra.y, acc[7 - k]);
                acc[7 - k] = dot2(lc.z, ra.z, acc[7 - k]);
                acc[7 - k] = dot2(lc.w, ra.w, acc[7 - k]);
            }
        }
    }

    const int t = t0 + tid;
    if (tid < TILE && t < T) {
        // ---- ITD: [B,T,16]
        float* oitd = out + ((size_t)b * T + t) * N_ITD;
#pragma unroll
        for (int q = 0; q < 4; ++q) {
            *(float4*)(oitd + q * 4) =
                make_float4(acc[q * 4 + 0], acc[q * 4 + 1], acc[q * 4 + 2], acc[q * 4 + 3]);
        }

        // ---- ILD: [B,T,8] after the ITD block
        const float ild = (sumL - sumR) / (sumL + sumR + 1e-6f);
        const float PREFS[8] = {-1.f, -0.71428573f, -0.42857143f, -0.14285714f,
                                0.14285715f, 0.42857143f, 0.71428573f, 1.f};
        float ov[8];
#pragma unroll
        for (int j = 0; j < 8; ++j) {
            const float z = (ild - PREFS[j]) * (1.0f / 0.3f);
            ov[j] = __expf(-0.5f * z * z);
        }
        float* oild = out + (size_t)NB * T * N_ITD + ((size_t)b * T + t) * N_ILD;
        *(float4*)(oild + 0) = make_float4(ov[0], ov[1], ov[2], ov[3]);
        *(float4*)(oild + 4) = make_float4(ov[4], ov[5], ov[6], ov[7]);
    }
}

extern "C" void kernel_launch(void* const* d_in, const int* in_sizes, int n_in,
                              void* d_out, int out_size, void* d_ws, size_t ws_size,
                              hipStream_t stream) {
    const float* L = (const float*)d_in[0];
    const float* R = (const float*)d_in[1];
    float* out = (float*)d_out;
    dim3 grid((T + TILE - 1) / TILE, NB);   // 64 x 16
    biaural_kernel<<<grid, dim3(TT), 0, stream>>>(L, R, out);
}